// Round 8
// baseline (5114.515 us; speedup 1.0000x reference)
//
#include <hip/hip_runtime.h>
#include <hip/hip_bf16.h>
#include <stdint.h>

// LSTM fused pipeline for B=256,S=512,D=256,H=256,O=128 on gfx950.
//
// Round-8 design: ZERO global memory in the recurrent serial chain.
//  - k_lstm: 16 independent blocks (one per 16-batch group), 512 thr (8 waves).
//    No cross-CU sync, no atomics, no flags, no h exchange.
//  - Wave w owns 128 gate-cols (q = w*8+nb, nb = hcp*4+gate): K-half kb0..3
//    resident in VGPRs (128/thread); kb4..7 streamed from L2 through a
//    32-VGPR window, chunk k+1 issued right after chunk k's MFMAs, kb4 chunk
//    for step t+1 issued BEFORE the barrier (weights constant => safe).
//  - Raw s_barrier with lgkmcnt(0)-only drain: global prefetches (x_{t+1},
//    weight chunk) stay in flight across the barrier (no vmcnt(0) drain).
//  - h double-buffered in LDS (8KB each, swizzled); ONE barrier per step.
//  - All 4 gates of (b,hc) in-thread (gate in MFMA N-frag index): no shuffles.
//  - xcat blobs per-(lstm thread): 4 x uint4 per thread-step, prefetched 1 ahead.

typedef unsigned short u16;
typedef unsigned int   u32;
typedef __bf16  bf16x8 __attribute__((ext_vector_type(8)));
typedef float   f32x4  __attribute__((ext_vector_type(4)));

union U4 { uint4 u; bf16x8 b; u16 s[8]; };

static __device__ __forceinline__ u16 f2b(float f){
  union { __hip_bfloat16 h; u16 u; } cv; cv.h = __float2bfloat16(f); return cv.u;
}
static __device__ __forceinline__ float b2f(u16 v){
  union { __hip_bfloat16 h; u16 u; } cv; cv.u = v; return __bfloat162float(cv.h);
}
static __device__ __forceinline__ float fsig(float x){
  return __builtin_amdgcn_rcpf(1.0f + __expf(-x));
}
static __device__ __forceinline__ float ftanh(float x){
  float ax = fabsf(x);
  float t  = __expf(-2.0f*ax);
  float r  = (1.0f - t) * __builtin_amdgcn_rcpf(1.0f + t);
  return copysignf(r, x);
}

struct PrepArgs {
  const float* wx[4]; const float* wh[4];
  const float* wxb[4]; const float* whb[4];
};

// ---------------------------------------------------------------- k_prep ----
// Column-block q = hcq*4 + gate (hcq = hc>>4); within block col = hc&15.
// B-frag slot: lane l holds W[q*16+(l&15)][kb*32+(l>>4)*8+e], slot=(q*8+kb)*64+l.
__global__ void k_prep(PrepArgs P, u16* __restrict__ WxP, u16* __restrict__ WhP,
                       float* __restrict__ biasj)
{
  int sIdx = blockIdx.x*256 + threadIdx.x;          // 32768 frag slots
  int lane = sIdx & 63, kb = (sIdx>>6)&7, jb = sIdx>>9;
  int hcl = lane & 15;
  int gate = jb & 3, hc = ((jb>>2)<<4) | hcl;
  int kbase = kb*32 + ((lane>>4)<<3);
  const float* wx = P.wx[gate];
  const float* wh = P.wh[gate];
  U4 ox, oh;
  #pragma unroll
  for (int e=0; e<8; e++){
    ox.s[e] = f2b(wx[hc*256 + kbase + e]);
    oh.s[e] = f2b(wh[hc*256 + kbase + e]);
  }
  *(uint4*)(WxP + (size_t)sIdx*8) = ox.u;
  *(uint4*)(WhP + (size_t)sIdx*8) = oh.u;
  if (sIdx < 1024){                                  // biasj[q*16 + hcl]
    int g2 = (sIdx>>4)&3, h2 = ((sIdx>>6)<<4)|(sIdx&15);
    biasj[sIdx] = P.wxb[g2][h2] + P.whb[g2][h2];
  }
}

// --------------------------------------------------------------- k_convx ----
__global__ void k_convx(const float* __restrict__ x, u16* __restrict__ xbf)
{
  int tid = blockIdx.x*256 + threadIdx.x;
  int ch = tid & 31;
  int b  = (tid>>5) & 255;
  int s  = tid >> 13;
  const float* src = x + ((size_t)b*512 + s)*256 + ch*8;
  float4 f0 = *(const float4*)(src);
  float4 f1 = *(const float4*)(src + 4);
  U4 o;
  o.s[0]=f2b(f0.x); o.s[1]=f2b(f0.y); o.s[2]=f2b(f0.z); o.s[3]=f2b(f0.w);
  o.s[4]=f2b(f1.x); o.s[5]=f2b(f1.y); o.s[6]=f2b(f1.z); o.s[7]=f2b(f1.w);
  u32 byteoff = (u32)(s*256 + b)*512u + (((u32)ch*16u) ^ ((u32)(b&7)<<4));
  *(uint4*)((char*)xbf + byteoff) = o.u;
}

// -------------------------------------------------------------- k_gemm_x ----
// Block: 128 batches (one s) x 256 gate-cols (quarter jt), K=256, 8 waves.
// Epilogue: xcat blob per (s,grp) = 32KB; lstm thread ltid's 64B:
// [hcp0: g,i][hcp0: f,o][hcp1: g,i][hcp1: f,o] as 4 uint4.
__launch_bounds__(512)
__global__ void k_gemm_x(const u16* __restrict__ xbf, const u16* __restrict__ WxP,
                         const float* __restrict__ biasj,
                         const float* __restrict__ bgg, const float* __restrict__ bii,
                         const float* __restrict__ bff, const float* __restrict__ boo,
                         u16* __restrict__ xcat)
{
  __shared__ u16 smA[128*256];                       // 64 KB, swizzled
  int tid = threadIdx.x;
  int bid = blockIdx.x;                              // 4096
  int mt = bid >> 2, jt = bid & 3;
  int s = mt >> 1, b0 = (mt & 1)*128;

  const uint4* srcA = (const uint4*)(xbf + (size_t)(s*256 + b0)*256);
  uint4* dstA = (uint4*)smA;
  #pragma unroll
  for (int i=0; i<8; i++) dstA[tid + i*512] = srcA[tid + i*512];
  __syncthreads();

  int lane = tid & 63, wid = tid >> 6;
  int wm = wid >> 2, wn = wid & 3;
  int r16 = lane & 15, khi = lane >> 4;

  f32x4 acc[4][4] = {};
  #pragma unroll
  for (int kb=0; kb<8; kb++){
    bf16x8 a[4];
    #pragma unroll
    for (int mb=0; mb<4; mb++){
      int row = wm*64 + mb*16 + r16;
      u32 abyte = (u32)row*512u + ((u32)((kb*32 + khi*8)*2) ^ ((u32)(row&7)<<4));
      U4 t; t.u = *(const uint4*)((const char*)smA + abyte);
      a[mb] = t.b;
    }
    #pragma unroll
    for (int nb=0; nb<4; nb++){
      int jbg = jt*16 + wn*4 + nb;                   // q = hcq*4 + gate(nb)
      U4 t; t.u = *(const uint4*)(WxP + (size_t)((jbg*8 + kb)*64 + lane)*8);
      #pragma unroll
      for (int mb=0; mb<4; mb++)
        acc[mb][nb] = __builtin_amdgcn_mfma_f32_16x16x32_bf16(a[mb], t.b, acc[mb][nb], 0,0,0);
    }
  }

  // hcq = jt*4+wn, hc = hcq*16 + r16; lstm wave = hcq>>1, hcp = hcq&1
  int hcq = jt*4 + wn;
  int hc  = hcq*16 + r16;
  int w_l = hcq >> 1, hcp = hcq & 1;
  int ltid = w_l*64 + khi*16 + r16;
  const float* btab[4] = {bgg, bii, bff, boo};
  float bj[4];
  #pragma unroll
  for (int nb=0; nb<4; nb++) bj[nb] = biasj[jt*256 + wn*64 + nb*16 + r16];

  #pragma unroll
  for (int mb=0; mb<4; mb++){
    int grp = (b0>>4) + wm*4 + mb;
    U4 o1, o2;
    #pragma unroll
    for (int nb=0; nb<4; nb++){
      #pragma unroll
      for (int r=0; r<4; r++){
        int b = b0 + wm*64 + mb*16 + khi*4 + r;
        float v = acc[mb][nb][r] + bj[nb] + btab[nb][b*256 + hc];
        if (nb < 2) o1.s[nb*4 + r] = f2b(v);
        else        o2.s[(nb-2)*4 + r] = f2b(v);
      }
    }
    size_t base = ((size_t)s*16 + grp)*16384 + (size_t)ltid*32 + (size_t)hcp*16;
    *(uint4*)(xcat + base)     = o1.u;               // g,i
    *(uint4*)(xcat + base + 8) = o2.u;               // f,o
  }
}

// ---------------------------------------------------------------- k_lstm ----
// 16 blocks x 512 thr (8 waves), fully independent. Wave w: cols q=w*8+nb,
// nb = hcp*4+gate, hc = (2w+hcp)*16+r16. Thread: b = khi*4+r.
// kb0..3 resident (128 VGPR), kb4..7 streamed via 32-VGPR window from L2.
__launch_bounds__(512, 2)
__global__ void k_lstm(const u16* __restrict__ xcat2, const u16* __restrict__ WhP,
                       float* __restrict__ hfin)
{
  __shared__ u16 hA[2][4096];                        // [par][b16][hc256] swz
  int tid = threadIdx.x, lane = tid & 63, w = tid >> 6;
  int grp = blockIdx.x;
  int r16 = lane & 15, khi = lane >> 4;

  // resident weights kb0..3
  bf16x8 wres[8][4];
  #pragma unroll
  for (int nb=0; nb<8; nb++){
    #pragma unroll
    for (int kb=0; kb<4; kb++){
      U4 t; t.u = *(const uint4*)(WhP + (size_t)((((w*8+nb)*8) + kb)*64 + lane)*8);
      wres[nb][kb] = t.b;
    }
  }

  for (int i=tid; i<8192; i+=512) ((u16*)hA)[i] = 0; // h0 = 0
  __syncthreads();

  // x_0 (4 x uint4 per thread)
  const u16* xp = xcat2 + (size_t)grp*16384 + (size_t)tid*32;
  uint4 xw0 = *(const uint4*)(xp);
  uint4 xw1 = *(const uint4*)(xp + 8);
  uint4 xw2 = *(const uint4*)(xp + 16);
  uint4 xw3 = *(const uint4*)(xp + 24);

  // stream window: issue kb4 chunk
  const u16* wsb = WhP + (size_t)lane*8;
  bf16x8 wstr[8];
  #pragma unroll
  for (int nb=0; nb<8; nb++){
    U4 t; t.u = *(const uint4*)(wsb + (size_t)((((w*8+nb)*8) + 4)*64)*8);
    wstr[nb] = t.b;
  }

  float c[2][4] = {{0.f,0.f,0.f,0.f},{0.f,0.f,0.f,0.f}};

  for (int t=0; t<512; t++){
    int cur = t & 1;
    f32x4 acc[8] = {};

    // resident MFMAs kb0..3 (LDS h reads)
    #pragma unroll
    for (int kb=0; kb<4; kb++){
      u32 ab = (u32)r16*512u + (((u32)(kb*64 + khi*16)) ^ ((u32)(r16&7)<<4));
      U4 ta; ta.u = *(const uint4*)((const char*)hA[cur] + ab);
      #pragma unroll
      for (int nb=0; nb<8; nb++)
        acc[nb] = __builtin_amdgcn_mfma_f32_16x16x32_bf16(ta.b, wres[nb][kb], acc[nb], 0,0,0);
    }

    // streamed MFMAs kb4..7; after consuming chunk kb, issue chunk kb+1
    // (kb7 issues next step's kb4 — weights constant, safe across barrier)
    #pragma unroll
    for (int kb=4; kb<8; kb++){
      u32 ab = (u32)r16*512u + (((u32)(kb*64 + khi*16)) ^ ((u32)(r16&7)<<4));
      U4 ta; ta.u = *(const uint4*)((const char*)hA[cur] + ab);
      #pragma unroll
      for (int nb=0; nb<8; nb++)
        acc[nb] = __builtin_amdgcn_mfma_f32_16x16x32_bf16(ta.b, wstr[nb], acc[nb], 0,0,0);
      int nkb = (kb < 7) ? kb+1 : 4;
      #pragma unroll
      for (int nb=0; nb<8; nb++){
        U4 tt; tt.u = *(const uint4*)(wsb + (size_t)((((w*8+nb)*8) + nkb)*64)*8);
        wstr[nb] = tt.b;
      }
    }

    // gates: all 4 gates of (b,hc) in-thread, p = hcp
    #pragma unroll
    for (int p=0; p<2; p++){
      U4 gi, fo;
      gi.u = (p==0) ? xw0 : xw2;
      fo.u = (p==0) ? xw1 : xw3;
      int hc = (2*w + p)*16 + r16;
      #pragma unroll
      for (int r=0; r<4; r++){
        float gv = ftanh(acc[p*4+0][r] + b2f(gi.s[r]));
        float iv = fsig (acc[p*4+1][r] + b2f(gi.s[4+r]));
        float fv = fsig (acc[p*4+2][r] + b2f(fo.s[r]));
        float ov = fsig (acc[p*4+3][r] + b2f(fo.s[4+r]));
        float cn = gv*iv + c[p][r]*fv;
        c[p][r] = cn;
        float hv = ftanh(cn)*ov;
        int b = khi*4 + r;
        if (t < 511){
          *(u16*)((char*)hA[cur^1] +
                  (((u32)b*512u + (u32)hc*2u) ^ ((u32)(b&7)<<4))) = f2b(hv);
        } else {
          hfin[(grp*16 + b)*256 + hc] = hv;
        }
      }
    }

    // x prefetch for t+1 (in flight across the raw barrier)
    {
      int tn = (t < 511) ? t+1 : 511;
      const u16* xn = xcat2 + ((size_t)tn*16 + (size_t)grp)*16384 + (size_t)tid*32;
      xw0 = *(const uint4*)(xn);
      xw1 = *(const uint4*)(xn + 8);
      xw2 = *(const uint4*)(xn + 16);
      xw3 = *(const uint4*)(xn + 24);
    }

    // raw barrier: drain LDS only (lgkmcnt), leave vmem prefetches in flight
    asm volatile("s_waitcnt lgkmcnt(0)" ::: "memory");
    __builtin_amdgcn_s_barrier();
    asm volatile("" ::: "memory");
    __builtin_amdgcn_sched_barrier(0);
  }
}

// ---------------------------------------------------------------- k_proj ----
__global__ void k_proj(const float* __restrict__ hfin, const float* __restrict__ Wph_w,
                       const float* __restrict__ Wph_b, const float* __restrict__ bp,
                       float* __restrict__ out)
{
  __shared__ float hrow[256];
  __shared__ float pbuf[128];
  int b = blockIdx.x, tid = threadIdx.x;             // 128 threads
  hrow[tid]       = hfin[b*256 + tid];
  hrow[tid + 128] = hfin[b*256 + 128 + tid];
  __syncthreads();
  const float* wr = Wph_w + (size_t)tid*256;
  float acc = Wph_b[tid] + bp[b*128 + tid];
  #pragma unroll 8
  for (int k=0; k<256; k++) acc += hrow[k]*wr[k];
  pbuf[tid] = acc;
  __syncthreads();
  float mx = -1e30f;
  for (int i=0; i<128; i++) mx = fmaxf(mx, pbuf[i]);
  float e = __expf(acc - mx);
  __syncthreads();
  pbuf[tid] = e;
  __syncthreads();
  float sum = 0.f;
  for (int i=0; i<128; i++) sum += pbuf[i];
  out[b*128 + tid] = e / sum;
}

// ----------------------------------------------------------------- launch ----
extern "C" void kernel_launch(void* const* d_in, const int* in_sizes, int n_in,
                              void* d_out, int out_size, void* d_ws, size_t ws_size,
                              hipStream_t stream)
{
  (void)in_sizes; (void)n_in; (void)out_size; (void)ws_size;
  const float* x     = (const float*)d_in[0];
  const float* Wph_w = (const float*)d_in[17];
  const float* Wph_b = (const float*)d_in[18];
  const float* bg    = (const float*)d_in[19];
  const float* bi    = (const float*)d_in[20];
  const float* bf    = (const float*)d_in[21];
  const float* bo    = (const float*)d_in[22];
  const float* bp    = (const float*)d_in[23];

  PrepArgs P;
  for (int g=0; g<4; g++){
    P.wx[g]  = (const float*)d_in[1 + 4*g];
    P.wxb[g] = (const float*)d_in[2 + 4*g];
    P.wh[g]  = (const float*)d_in[3 + 4*g];
    P.whb[g] = (const float*)d_in[4 + 4*g];
  }

  char* ws = (char*)d_ws;
  u16*   xcat  = (u16*)(ws);                                   // 268435456 B
  u16*   xbf   = (u16*)(ws + 268435456);                       //  67108864 B (dead after k_gemm_x)
  u16*   WxP   = (u16*)(ws + 268435456 + 67108864);            //    524288 B
  u16*   WhP   = (u16*)(ws + 268435456 + 67108864 + 524288);   //    524288 B
  float* biasj = (float*)(ws + 268435456 + 67108864 + 1048576);//      4096 B
  float* hfin  = (float*)(ws + 268435456 + 67108864 + 1048576 + 4096); // 262144 B

  k_prep <<<128,   256, 0, stream>>>(P, WxP, WhP, biasj);
  k_convx<<<16384, 256, 0, stream>>>(x, xbf);
  k_gemm_x<<<4096, 512, 0, stream>>>(xbf, WxP, biasj, bg, bi, bf, bo, xcat);
  k_lstm <<<16,    512, 0, stream>>>(xcat, WhP, hfin);
  k_proj <<<256,   128, 0, stream>>>(hfin, Wph_w, Wph_b, bp, (float*)d_out);
}